// Round 11
// baseline (1266.313 us; speedup 1.0000x reference)
//
#include <hip/hip_runtime.h>
#include <math.h>

#define BSZ   384
#define BM1   383
#define DIM   256
#define NZTOT 768
#define NBLK  96
#define RPB   4
#define TPB   768
#define NITER 100
#define RINGD 8
#define ARRFULL NBLK
#define DYNB  (2 * RINGD * RPB * BSZ * 4)   // wpart(49152) + ring(49152) = 98304 B

// ---- ws layout (float offsets) ----
#define OFF_Z    0          // 768*256
#define OFF_NRM  196608     // 768
#define OFF_K    197376     // 384*768
#define OFF_KP   492288     // 384*384 packed KK
#define OFF_A    639744     // 384*383 final alpha
#define OFF_NUM  786816     // NITER (pad 128)
#define OFF_DEN  786944
#define OFF_ARR  787072
#define OFF_LOSS 787200     // 2 doubles

__device__ __forceinline__ void fma4(float4& a, const float4 k, const float s) {
    a.x = fmaf(k.x, s, a.x); a.y = fmaf(k.y, s, a.y);
    a.z = fmaf(k.z, s, a.z); a.w = fmaf(k.w, s, a.w);
}

__global__ void init_kernel(float* num, float* den, int* arr, double* lossAcc) {
    int t = threadIdx.x;
    if (t < NITER) { num[t] = 0.f; den[t] = 0.f; arr[t] = 0; }
    if (t < 2) lossAcc[t] = 0.0;
}

__global__ void __launch_bounds__(64)
norm_kernel(const float* __restrict__ xis, const float* __restrict__ xjs,
            float* __restrict__ Z, float* __restrict__ nrm2) {
    const int row  = blockIdx.x;
    const int lane = threadIdx.x;
    const float* src = (row < BSZ) ? (xis + (size_t)row * DIM)
                                   : (xjs + (size_t)(row - BSZ) * DIM);
    float4 x = reinterpret_cast<const float4*>(src)[lane];
    float s = x.x*x.x + x.y*x.y + x.z*x.z + x.w*x.w;
    for (int m = 32; m; m >>= 1) s += __shfl_xor(s, m, 64);
    float nrm = sqrtf(s);
    float4 z;
    z.x = x.x / nrm; z.y = x.y / nrm; z.z = x.z / nrm; z.w = x.w / nrm;
    reinterpret_cast<float4*>(Z + (size_t)row * DIM)[lane] = z;
    float s2 = z.x*z.x + z.y*z.y + z.z*z.z + z.w*z.w;
    for (int m = 32; m; m >>= 1) s2 += __shfl_xor(s2, m, 64);
    if (lane == 0) nrm2[row] = s2;
}

__global__ void __launch_bounds__(256)
k_kernel(const float* __restrict__ Z, const float* __restrict__ nrm2,
         float* __restrict__ Km, float* __restrict__ KKp) {
    const int i = blockIdx.x;
    const int j = blockIdx.y * 256 + threadIdx.x;
    __shared__ float zi[DIM];
    zi[threadIdx.x] = Z[(size_t)i * DIM + threadIdx.x];
    __syncthreads();
    const float4* zr = reinterpret_cast<const float4*>(Z + (size_t)j * DIM);
    float acc = 0.f;
    #pragma unroll 8
    for (int k = 0; k < DIM/4; ++k) {
        float4 v = zr[k];
        acc = fmaf(zi[4*k+0], v.x, acc);
        acc = fmaf(zi[4*k+1], v.y, acc);
        acc = fmaf(zi[4*k+2], v.z, acc);
        acc = fmaf(zi[4*k+3], v.w, acc);
    }
    float sq = nrm2[i] + nrm2[j] - 2.f * acc;
    sq = fmaxf(sq, 0.f);
    const float val = expf(-0.1f * sq);
    Km[(size_t)i * NZTOT + j] = val;
    if (j < BSZ) KKp[(size_t)i * BSZ + j] = val;
}

// ---- phase-2 macros (named regs, compile-time indices) ----
#define KLD(K0,K1,K2,K3, G) do {                                             \
    K0 = KO[((G)*4+0)*96]; K1 = KO[((G)*4+1)*96];                            \
    K2 = KO[((G)*4+2)*96]; K3 = KO[((G)*4+3)*96]; } while (0)

#define KFMA(K0,K1,K2,K3, G) do {                                            \
    const float4 zr0 = zrow4[0][zb4 + (G)];                                  \
    fma4(acc0, K0, zr0.x); fma4(acc0, K1, zr0.y);                            \
    fma4(acc0, K2, zr0.z); fma4(acc0, K3, zr0.w);                            \
    const float4 zr1 = zrow4[1][zb4 + (G)];                                  \
    fma4(acc1, K0, zr1.x); fma4(acc1, K1, zr1.y);                            \
    fma4(acc1, K2, zr1.z); fma4(acc1, K3, zr1.w);                            \
    const float4 zr2 = zrow4[2][zb4 + (G)];                                  \
    fma4(acc2, K0, zr2.x); fma4(acc2, K1, zr2.y);                            \
    fma4(acc2, K2, zr2.z); fma4(acc2, K3, zr2.w);                            \
    const float4 zr3 = zrow4[3][zb4 + (G)];                                  \
    fma4(acc3, K0, zr3.x); fma4(acc3, K1, zr3.y);                            \
    fma4(acc3, K2, zr3.z); fma4(acc3, K3, zr3.w); } while (0)

__global__ void __launch_bounds__(TPB, 1)
pgd_kernel(const float* __restrict__ Km, const float* __restrict__ KKp,
           const float* __restrict__ alpha_init,
           float* __restrict__ afin, float* num, float* den, int* arr) {
    const int g    = blockIdx.x;     // 0..95
    const int c    = threadIdx.x;    // 0..767
    const int lane = c & 63;
    const int wv   = c >> 6;         // 0..11
    const int o    = c / 96;         // octant: J rows [48o, 48o+48)
    const int u    = c - o * 96;     // owns cols 4u..4u+3
    const int zb4  = 12 * o;

    extern __shared__ float dynl[];
    float* const wpart = dynl;                    // [8][RPB][384]
    float* const ringb = dynl + 8 * RPB * BSZ;    // [RINGD][RPB][384]

    __shared__ float4 zrow4[RPB][98];
    __shared__ float  rscr[12][10];   // per-wave: zn0..3, kbzn0..3, nump, an2
    __shared__ float  SD[8];          // S0..3, D0..3
    __shared__ unsigned long long scanm[2];

    const bool act = (c < BSZ);

    // ---- per-row init (column thread c; diagonal c==b inert) ----
    float a[RPB], kb[RPB]; bool vld[RPB];
    #pragma unroll
    for (int r = 0; r < RPB; ++r) {
        const int b = g * RPB + r;
        vld[r] = act && (c != b);
        kb[r]  = act ? Km[(size_t)b * NZTOT + c] : 0.f;
        float v = 0.f;
        if (vld[r]) {
            const int i = c - (c > b ? 1 : 0);
            v = alpha_init[(size_t)b * BM1 + i];
            v = fminf(fmaxf(v, 0.f), 1.f);
        }
        a[r] = v;
    }

    const float4* __restrict__ KO = reinterpret_cast<const float4*>(KKp)
                                    + (size_t)(48 * o) * 96 + u;

    // ---- prologue "phase 3" for t=0: z(0)=a, reductions ----
    {
        float an2 = 0.f;
        float vv[10];
        #pragma unroll
        for (int r = 0; r < RPB; ++r) {
            if (act) ((float*)&zrow4[r][0])[c] = a[r];
            vv[r]     = a[r];
            vv[4 + r] = kb[r] * a[r];
            an2 += a[r] * a[r];
        }
        vv[8] = 0.f; vv[9] = an2;
        #pragma unroll
        for (int k = 0; k < 10; ++k) {
            float x = vv[k];
            x += __shfl_down(x, 32, 64); x += __shfl_down(x, 16, 64);
            x += __shfl_down(x,  8, 64); x += __shfl_down(x,  4, 64);
            x += __shfl_down(x,  2, 64); x += __shfl_down(x,  1, 64);
            if (lane == 0) rscr[wv][k] = x;
        }
        if (c < 2) scanm[c] = 0ULL;
    }
    __syncthreads();

    int stopT = -1;
    int sstate = 0, okv = 0, aval = 0;
    float nnv = 0.f, ddv = 1.f;

    for (int t = 0; t < NITER; ++t) {
        // ---- top: stop decision (from ballots of t-1) ----
        {
            const unsigned long long m0 = scanm[0], m1 = scanm[1];
            const int st = m0 ? (__ffsll(m0) - 1) : (m1 ? 63 + __ffsll(m1) : -1);
            if (st >= 0) { stopT = st; break; }
        }
        if (c < 8) {
            float s = 0.f;
            #pragma unroll
            for (int w = 0; w < 12; ++w) s += rscr[w][c];
            SD[c] = s;
        }
        // ---- fire-and-forget publish of iteration t-1 (c==0) ----
        if (c == 0) {
            float nb = 0.f, db = 0.f;
            #pragma unroll
            for (int w = 0; w < 12; ++w) { nb += rscr[w][8]; db += rscr[w][9]; }
            __hip_atomic_fetch_add(&den[t], db, __ATOMIC_RELAXED, __HIP_MEMORY_SCOPE_AGENT);
            if (t > 0) {
                __hip_atomic_fetch_add(&num[t - 1], nb, __ATOMIC_RELAXED, __HIP_MEMORY_SCOPE_AGENT);
                __hip_atomic_fetch_add(&arr[t - 1], 1, __ATOMIC_RELEASE, __HIP_MEMORY_SCOPE_AGENT);
            }
        }
        // ---- scan loads (state machine; evaluated in phase 3) ----
        if (c < NITER) {
            if (sstate == 0) {
                aval = __hip_atomic_load(&arr[c], __ATOMIC_RELAXED, __HIP_MEMORY_SCOPE_AGENT);
            } else if (sstate == 1) {
                nnv = __hip_atomic_load(&num[c], __ATOMIC_RELAXED, __HIP_MEMORY_SCOPE_AGENT);
                ddv = __hip_atomic_load(&den[c], __ATOMIC_RELAXED, __HIP_MEMORY_SCOPE_AGENT);
            }
        }

        // ---- phase 2: octant matvec, 12 groups, depth-3 pipeline ----
        float4 acc0 = make_float4(0.f,0.f,0.f,0.f);
        float4 acc1 = make_float4(0.f,0.f,0.f,0.f);
        float4 acc2 = make_float4(0.f,0.f,0.f,0.f);
        float4 acc3 = make_float4(0.f,0.f,0.f,0.f);
        {
            float4 kA0,kA1,kA2,kA3, kB0,kB1,kB2,kB3, kC0,kC1,kC2,kC3;
            KLD(kA0,kA1,kA2,kA3, 0);
            KLD(kB0,kB1,kB2,kB3, 1);
            KLD(kC0,kC1,kC2,kC3, 2);  KFMA(kA0,kA1,kA2,kA3, 0);
            KLD(kA0,kA1,kA2,kA3, 3);  KFMA(kB0,kB1,kB2,kB3, 1);
            KLD(kB0,kB1,kB2,kB3, 4);  KFMA(kC0,kC1,kC2,kC3, 2);
            KLD(kC0,kC1,kC2,kC3, 5);  KFMA(kA0,kA1,kA2,kA3, 3);
            KLD(kA0,kA1,kA2,kA3, 6);  KFMA(kB0,kB1,kB2,kB3, 4);
            KLD(kB0,kB1,kB2,kB3, 7);  KFMA(kC0,kC1,kC2,kC3, 5);
            KLD(kC0,kC1,kC2,kC3, 8);  KFMA(kA0,kA1,kA2,kA3, 6);
            KLD(kA0,kA1,kA2,kA3, 9);  KFMA(kB0,kB1,kB2,kB3, 7);
            KLD(kB0,kB1,kB2,kB3, 10); KFMA(kC0,kC1,kC2,kC3, 8);
            KLD(kC0,kC1,kC2,kC3, 11); KFMA(kA0,kA1,kA2,kA3, 9);
            KFMA(kB0,kB1,kB2,kB3, 10);
            KFMA(kC0,kC1,kC2,kC3, 11);
        }
        *reinterpret_cast<float4*>(&wpart[(o * RPB + 0) * BSZ + 4*u]) = acc0;
        *reinterpret_cast<float4*>(&wpart[(o * RPB + 1) * BSZ + 4*u]) = acc1;
        *reinterpret_cast<float4*>(&wpart[(o * RPB + 2) * BSZ + 4*u]) = acc2;
        *reinterpret_cast<float4*>(&wpart[(o * RPB + 3) * BSZ + 4*u]) = acc3;
        __syncthreads();   // B2

        // ---- phase 3: step t, prepare t+1, reductions, scan eval ----
        float nump = 0.f, an2 = 0.f;
        float zn[RPB] = {0.f, 0.f, 0.f, 0.f};
        if (act) {
            const int slot = t & (RINGD - 1);
            const float beta1 = (float)(t + 1) / ((float)(t + 1) + 3.0f);
            #pragma unroll
            for (int r = 0; r < RPB; ++r) {
                float w = 0.f;
                #pragma unroll
                for (int oo = 0; oo < 8; ++oo) w += wpart[(oo * RPB + r) * BSZ + c];
                const float z = ((const float*)&zrow4[r][0])[c];
                float an = 0.f;
                if (vld[r]) {
                    const float grad = SD[r] * (1.f - kb[r]) + 0.1f * z + w - SD[4 + r] - 2.0f;
                    an = z - 0.001f * grad;
                    an = fminf(fmaxf(an, 0.f), 1.f);
                }
                const float d = an - a[r];
                nump += d * d;
                an2  += an * an;
                zn[r] = an + beta1 * (an - a[r]);
                ringb[((size_t)slot * RPB + r) * BSZ + c] = an;
                a[r] = an;
            }
            #pragma unroll
            for (int r = 0; r < RPB; ++r) ((float*)&zrow4[r][0])[c] = zn[r];
        }
        {
            float vv[10] = { zn[0], zn[1], zn[2], zn[3],
                             kb[0]*zn[0], kb[1]*zn[1], kb[2]*zn[2], kb[3]*zn[3],
                             nump, an2 };
            #pragma unroll
            for (int k = 0; k < 10; ++k) {
                float x = vv[k];
                x += __shfl_down(x, 32, 64); x += __shfl_down(x, 16, 64);
                x += __shfl_down(x,  8, 64); x += __shfl_down(x,  4, 64);
                x += __shfl_down(x,  2, 64); x += __shfl_down(x,  1, 64);
                if (lane == 0) rscr[wv][k] = x;
            }
        }
        // ---- scan state transitions + ballot ----
        if (c < NITER) {
            if (sstate == 0) { if (aval == ARRFULL) sstate = 1; }
            else if (sstate == 1) {
                okv = (sqrtf(nnv) / (sqrtf(ddv) + 1e-8f) < 0.01f) ? 1 : 0;
                sstate = 2;
            }
        }
        {
            const unsigned long long bm = __ballot(okv);
            if (lane == 0 && wv < 2) scanm[wv] = bm;
        }
        __syncthreads();   // B3
    }

    // ---- finalize ----
    if (act) {
        #pragma unroll
        for (int r = 0; r < RPB; ++r) {
            const int b = g * RPB + r;
            if (vld[r]) {
                const float av = (stopT >= 0)
                    ? ringb[((size_t)(stopT & (RINGD - 1)) * RPB + r) * BSZ + c]
                    : a[r];
                const int i = c - (c > b ? 1 : 0);
                afin[(size_t)b * BM1 + i] = av;
            }
        }
    }
}

__global__ void __launch_bounds__(384)
loss_kernel(const float* __restrict__ Km, const float* __restrict__ afin,
            double* lossAcc) {
    const int b    = blockIdx.x;
    const int tid  = threadIdx.x;
    const int lane = tid & 63;
    const int wv   = tid >> 6;
    __shared__ double dscr[6][2];
    double np = 0.0, pp = 0.0;
    if (tid < BM1) {
        const float ay = afin[(size_t)b * BM1 + tid];
        const int   I  = tid + (tid >= b);
        np = (double)ay * (double)Km[(size_t)I * NZTOT + BSZ + b];
        pp = (double)ay * (double)Km[(size_t)b * NZTOT + BSZ + b];
    }
    for (int o = 32; o; o >>= 1) { np += __shfl_down(np, o, 64); pp += __shfl_down(pp, o, 64); }
    if (lane == 0) { dscr[wv][0] = np; dscr[wv][1] = pp; }
    __syncthreads();
    if (tid == 0) {
        double nb = 0.0, pb = 0.0;
        for (int w = 0; w < 6; ++w) { nb += dscr[w][0]; pb += dscr[w][1]; }
        __hip_atomic_fetch_add(&lossAcc[0], nb, __ATOMIC_RELAXED, __HIP_MEMORY_SCOPE_AGENT);
        __hip_atomic_fetch_add(&lossAcc[1], pb, __ATOMIC_RELAXED, __HIP_MEMORY_SCOPE_AGENT);
    }
}

__global__ void fin_kernel(const double* lossAcc, float* out) {
    out[0] = expf((float)(lossAcc[0] / 384.0 - lossAcc[1] / 384.0));
}

extern "C" void kernel_launch(void* const* d_in, const int* in_sizes, int n_in,
                              void* d_out, int out_size, void* d_ws, size_t ws_size,
                              hipStream_t stream) {
    const float* xis        = (const float*)d_in[0];
    const float* xjs        = (const float*)d_in[1];
    const float* alpha_init = (const float*)d_in[2];
    float* ws   = (float*)d_ws;
    float* Z    = ws + OFF_Z;
    float* nrm2 = ws + OFF_NRM;
    float* Km   = ws + OFF_K;
    float* KKp  = ws + OFF_KP;
    float* afin = ws + OFF_A;
    float* num  = ws + OFF_NUM;
    float* den  = ws + OFF_DEN;
    int*   arr  = (int*)(ws + OFF_ARR);
    double* lossAcc = (double*)(ws + OFF_LOSS);
    float* out  = (float*)d_out;

    hipFuncSetAttribute((const void*)pgd_kernel,
                        hipFuncAttributeMaxDynamicSharedMemorySize, DYNB);

    hipLaunchKernelGGL(init_kernel, dim3(1), dim3(128), 0, stream, num, den, arr, lossAcc);
    hipLaunchKernelGGL(norm_kernel, dim3(NZTOT), dim3(64), 0, stream, xis, xjs, Z, nrm2);
    hipLaunchKernelGGL(k_kernel, dim3(BSZ, 3), dim3(256), 0, stream, Z, nrm2, Km, KKp);
    hipLaunchKernelGGL(pgd_kernel, dim3(NBLK), dim3(TPB), DYNB, stream,
                       Km, KKp, alpha_init, afin, num, den, arr);
    hipLaunchKernelGGL(loss_kernel, dim3(BSZ), dim3(384), 0, stream, Km, afin, lossAcc);
    hipLaunchKernelGGL(fin_kernel, dim3(1), dim3(1), 0, stream, lossAcc, out);
}